// Round 1
// baseline (108.292 us; speedup 1.0000x reference)
//
#include <hip/hip_runtime.h>

// CurvatureLoss: B=4, N=4096, fp32.
// R8: counters show VALUBusy 96% but R6 history shows inst cuts under-deliver
// -> co-limited by per-wave-step VMEM (2x dwordx4/step = ~20.8 TB/s L1, >50%
// of L1 ceiling) + per-step overhead. Fix: amortize -- 4 queries/wave (QPB=16)
// halves loads/addr/rotation per query; top-3 -> top-2 trackers via explicit
// self-zap at the (wave-uniform) self step kills one med3 per tracker per step
// and the post-loop collapse. Same embed6/ballot recovery, prefetch distance 2.

constexpr int BB   = 4;
constexpr int NN   = 4096;
constexpr int QPW  = 4;              // queries per wave
constexpr int QPB  = 16;             // 4 waves x 4 queries
constexpr int CPB  = 64;             // chunk = lane
constexpr int NK   = NN / CPB;       // 64 steps; candidate j = 64*k + lane
constexpr int NBLK = BB * NN / QPB;  // 1024 blocks
constexpr float NEGBIG = -3.402823466e+38f;

__global__ __launch_bounds__(256) void pack_kernel(
    const float* __restrict__ ori, const float* __restrict__ adv,
    float4* __restrict__ oriP, float4* __restrict__ advP)
{
    const int i = blockIdx.x * blockDim.x + threadIdx.x;
    if (i < BB * NN) {
        float x = ori[3 * i], y = ori[3 * i + 1], z = ori[3 * i + 2];
        oriP[i] = make_float4(x, y, z, 0.5f * (x * x + y * y + z * z));
        x = adv[3 * i]; y = adv[3 * i + 1]; z = adv[3 * i + 2];
        advP[i] = make_float4(x, y, z, 0.5f * (x * x + y * y + z * z));
    }
}

__device__ __forceinline__ float embed6(float t, unsigned eb) {
    return __uint_as_float((__float_as_uint(t) & 0xFFFFFFC0u) | eb);  // v_and_or_b32
}

__device__ __forceinline__ float fmed3(float a, float b, float c) {
    return __builtin_amdgcn_fmed3f(a, b, c);
}

// v: merged key; p0/p1: this lane's partials. Wave-uniform result.
// Lowest matching lane = smallest global index (j = 64k + lane).
__device__ __forceinline__ int recover_j(float v, float p0, float p1) {
    unsigned long long m = __ballot((p0 == v) || (p1 == v));
    const int lane = (int)__ffsll(m) - 1;
    const int k = (NK - 1) - (int)(__float_as_uint(v) & (unsigned)(NK - 1));
    return (k << 6) | lane;
}

__device__ __forceinline__ float unit_absdot4(const float4* __restrict__ pc, int i,
                                              float px, float py, float pz,
                                              float nx, float ny, float nz) {
    const float4 c = pc[i];
    const float vx = c.x - px, vy = c.y - py, vz = c.z - pz;
    const float s  = vx * vx + vy * vy + vz * vz + 1e-12f;
    return fabsf((vx * nx + vy * ny + vz * nz) * (1.0f / sqrtf(s)));
}

__global__ __launch_bounds__(256, 4) void knn_kernel(
    const float4* __restrict__ oriP, const float4* __restrict__ advP,
    const float* __restrict__ nrm, float* __restrict__ partial,
    float* __restrict__ out, int use_partial)
{
    const int tid = threadIdx.x;
    const int ch  = tid & 63;          // chunk = lane
    const int qs  = tid >> 6;          // wave id 0..3
    const int b   = blockIdx.x >> 8;   // / (N/QPB = 256)
    const int qt  = blockIdx.x & 255;
    const int qb  = qt * QPB + qs * QPW;   // first query of this wave

    const float4* __restrict__ ob = oriP + (size_t)b * NN;
    const float4* __restrict__ ab = advP + (size_t)b * NN;
    const float*  __restrict__ nb = nrm  + (size_t)b * NN * 3;

    float4 qo[QPW], qa[QPW];
    #pragma unroll
    for (int i = 0; i < QPW; ++i) { qo[i] = ob[qb + i]; qa[i] = ab[qb + i]; }

    // top-2 trackers (max = closest); self is zapped at its (uniform) step.
    float oA[QPW], oB[QPW], aA[QPW], aB[QPW], mm[QPW];
    #pragma unroll
    for (int i = 0; i < QPW; ++i) {
        oA[i] = NEGBIG; oB[i] = NEGBIG;
        aA[i] = NEGBIG; aB[i] = NEGBIG;
        mm[i] = NEGBIG;
    }

    const int kself = qb >> 6;         // all 4 queries share one self step
    const int sl    = qb & 63;         // self lanes sl..sl+3

    const float4* __restrict__ op = ob + ch;
    const float4* __restrict__ ap = ab + ch;

    // one step: 12 dots (3 matrices x 4 queries) + top-2/argmax updates
    auto stepf = [&](const float4& co, const float4& ca, unsigned eb, bool selfstep) {
        float ko[QPW], ka[QPW], km[QPW];
        #pragma unroll
        for (int i = 0; i < QPW; ++i) {
            float t;
            t = fmaf(qo[i].z, co.z, -co.w); t = fmaf(qo[i].y, co.y, t); t = fmaf(qo[i].x, co.x, t);
            ko[i] = embed6(t, eb);
            t = fmaf(qa[i].z, co.z, -co.w); t = fmaf(qa[i].y, co.y, t); t = fmaf(qa[i].x, co.x, t);
            km[i] = embed6(t, eb);
            t = fmaf(qa[i].z, ca.z, -ca.w); t = fmaf(qa[i].y, ca.y, t); t = fmaf(qa[i].x, ca.x, t);
            ka[i] = embed6(t, eb);
        }
        if (selfstep) {                 // wave-uniform branch, taken once in 64
            #pragma unroll
            for (int i = 0; i < QPW; ++i) {
                const bool s = (ch == sl + i);
                ko[i] = s ? NEGBIG : ko[i];   // self excluded from ori-ori
                ka[i] = s ? NEGBIG : ka[i];   // self excluded from adv-adv
                // km (adv->ori argmax) keeps self: ref argmin is over ALL ori
            }
        }
        #pragma unroll
        for (int i = 0; i < QPW; ++i) {
            oB[i] = fmed3(oA[i], oB[i], ko[i]); oA[i] = fmaxf(oA[i], ko[i]);
            aB[i] = fmed3(aA[i], aB[i], ka[i]); aA[i] = fmaxf(aA[i], ka[i]);
            mm[i] = fmaxf(mm[i], km[i]);
        }
    };

    // software pipeline, prefetch distance 2; rotations become renames
    // under unroll 2; last 2 steps peeled (no OOB prefetch).
    float4 c0o = op[0 * CPB], c0a = ap[0 * CPB];
    float4 c1o = op[1 * CPB], c1a = ap[1 * CPB];

    #pragma unroll 2
    for (int k = 0; k < NK - 2; ++k) {
        const float4 c2o = op[(k + 2) * CPB];
        const float4 c2a = ap[(k + 2) * CPB];
        stepf(c0o, c0a, (unsigned)(NK - 1 - k), k == kself);
        c0o = c1o; c0a = c1a;
        c1o = c2o; c1a = c2a;
    }
    stepf(c0o, c0a, 1u, (NK - 2) == kself);
    stepf(c1o, c1a, 0u, (NK - 1) == kself);

    // save per-lane partials for index recovery
    float soA[QPW], soB[QPW], saA[QPW], saB[QPW], sm[QPW];
    #pragma unroll
    for (int i = 0; i < QPW; ++i) {
        soA[i] = oA[i]; soB[i] = oB[i];
        saA[i] = aA[i]; saB[i] = aB[i];
        sm[i]  = mm[i];
    }

    // wave butterfly top-2 merge: A=max(a0,b0); B=max(min(a0,b0),max(a1,b1))
    #pragma unroll
    for (int off = 1; off < 64; off <<= 1) {
        #pragma unroll
        for (int i = 0; i < QPW; ++i) {
            float r0, r1, mn;
            r0 = __shfl_xor(oA[i], off); r1 = __shfl_xor(oB[i], off);
            mn = fminf(oA[i], r0); oA[i] = fmaxf(oA[i], r0); oB[i] = fmaxf(mn, fmaxf(oB[i], r1));
            r0 = __shfl_xor(aA[i], off); r1 = __shfl_xor(aB[i], off);
            mn = fminf(aA[i], r0); aA[i] = fmaxf(aA[i], r0); aB[i] = fmaxf(mn, fmaxf(aB[i], r1));
            mm[i] = fmaxf(mm[i], __shfl_xor(mm[i], off));
        }
    }

    // recover global candidate indices (wave-uniform, ballot-based)
    int jo0[QPW], jo1[QPW], ja0[QPW], ja1[QPW], jm[QPW];
    #pragma unroll
    for (int i = 0; i < QPW; ++i) {
        jo0[i] = recover_j(oA[i], soA[i], soB[i]);
        jo1[i] = recover_j(oB[i], soA[i], soB[i]);
        ja0[i] = recover_j(aA[i], saA[i], saB[i]);
        ja1[i] = recover_j(aB[i], saA[i], saB[i]);
        jm[i]  = recover_j(mm[i], sm[i], sm[i]);
    }

    float val = 0.0f;
    if (ch < QPW) {                     // lane i -> query qb+i
        const int c1 = ch & 1, c2 = ch >> 1;
        auto sel_i = [&](const int* a) {
            const int x = c1 ? a[1] : a[0];
            const int y = c1 ? a[3] : a[2];
            return c2 ? y : x;
        };
        auto sel_4 = [&](const float4* a) {
            const float4 x = c1 ? a[1] : a[0];
            const float4 y = c1 ? a[3] : a[2];
            return c2 ? y : x;
        };
        const int    q   = qb + ch;
        const float4 qoS = sel_4(qo);
        const float4 qaS = sel_4(qa);
        const int io0 = sel_i(jo0), io1 = sel_i(jo1);
        const int ia0 = sel_i(ja0), ia1 = sel_i(ja1);
        const int im  = sel_i(jm);

        const float nx = nb[3 * q], ny = nb[3 * q + 1], nz = nb[3 * q + 2];
        const float ok = 0.5f * (unit_absdot4(ob, io0, qoS.x, qoS.y, qoS.z, nx, ny, nz) +
                                 unit_absdot4(ob, io1, qoS.x, qoS.y, qoS.z, nx, ny, nz));
        const float ax = nb[3 * im], ay = nb[3 * im + 1], az = nb[3 * im + 2];
        const float ak = 0.5f * (unit_absdot4(ab, ia0, qaS.x, qaS.y, qaS.z, ax, ay, az) +
                                 unit_absdot4(ab, ia1, qaS.x, qaS.y, qaS.z, ax, ay, az));
        const float d = ak - ok;
        val = d * d;
    }
    val += __shfl_down(val, 2);         // lanes 0..3 -> lane 0
    val += __shfl_down(val, 1);

    __shared__ float sval[4];
    if (ch == 0) sval[qs] = val;
    __syncthreads();
    if (tid == 0) {
        const float s = sval[0] + sval[1] + sval[2] + sval[3];
        if (use_partial) partial[blockIdx.x] = s;
        else             atomicAdd(out, s * (1.0f / (float)(BB * NN)));
    }
}

__global__ __launch_bounds__(256) void reduce_kernel(
    const float* __restrict__ partial, float* __restrict__ out)
{
    const int tid = threadIdx.x;
    float s = 0.0f;
    #pragma unroll
    for (int i = tid; i < NBLK; i += 256) s += partial[i];
    #pragma unroll
    for (int off = 32; off > 0; off >>= 1) s += __shfl_down(s, off);
    __shared__ float ls[4];
    if ((tid & 63) == 0) ls[tid >> 6] = s;
    __syncthreads();
    if (tid == 0)
        out[0] = (ls[0] + ls[1] + ls[2] + ls[3]) * (1.0f / (float)(BB * NN));
}

extern "C" void kernel_launch(void* const* d_in, const int* in_sizes, int n_in,
                              void* d_out, int out_size, void* d_ws, size_t ws_size,
                              hipStream_t stream) {
    const float* ori = (const float*)d_in[0];
    const float* adv = (const float*)d_in[1];
    const float* nrm = (const float*)d_in[2];
    float* out = (float*)d_out;

    float4* oriP = (float4*)d_ws;                    // 256 KB
    float4* advP = oriP + (size_t)BB * NN;           // 256 KB
    float*  part = (float*)(advP + (size_t)BB * NN); // 4 KB
    const size_t need = (size_t)2 * BB * NN * sizeof(float4) + NBLK * sizeof(float);
    const int use_partial = (ws_size >= need) ? 1 : 0;

    if (!use_partial)
        hipMemsetAsync(out, 0, sizeof(float), stream);

    hipLaunchKernelGGL(pack_kernel, dim3((BB * NN + 255) / 256), dim3(256), 0, stream,
                       ori, adv, oriP, advP);
    hipLaunchKernelGGL(knn_kernel, dim3(NBLK), dim3(256), 0, stream,
                       oriP, advP, nrm, part, out, use_partial);
    if (use_partial)
        hipLaunchKernelGGL(reduce_kernel, dim3(1), dim3(256), 0, stream, part, out);
}

// Round 2
// 105.663 us; speedup vs baseline: 1.0249x; 1.0249x over previous
//
#include <hip/hip_runtime.h>

// CurvatureLoss: B=4, N=4096, fp32.
// R9: R8's QPW=4 regressed because the epilogue passed local arrays BY POINTER
// (sel_i/sel_4), defeating SROA -> promote-alloca to LDS (16.9KB) + scratch
// spills (WRITE_SIZE 4MB) + occupancy halved. Fix: pointer-free constant-index
// selection; arrays stay SROA-able -> all-register. Same QPW=4 amortization
// (loads/addr/overhead per query halved vs QPW=2), top-2 trackers + self-zap,
// embed6/ballot recovery, prefetch distance 2.

constexpr int BB   = 4;
constexpr int NN   = 4096;
constexpr int QPW  = 4;              // queries per wave
constexpr int QPB  = 16;             // 4 waves x 4 queries
constexpr int CPB  = 64;             // chunk = lane
constexpr int NK   = NN / CPB;       // 64 steps; candidate j = 64*k + lane
constexpr int NBLK = BB * NN / QPB;  // 1024 blocks
constexpr float NEGBIG = -3.402823466e+38f;

__global__ __launch_bounds__(256) void pack_kernel(
    const float* __restrict__ ori, const float* __restrict__ adv,
    float4* __restrict__ oriP, float4* __restrict__ advP)
{
    const int i = blockIdx.x * blockDim.x + threadIdx.x;
    if (i < BB * NN) {
        float x = ori[3 * i], y = ori[3 * i + 1], z = ori[3 * i + 2];
        oriP[i] = make_float4(x, y, z, 0.5f * (x * x + y * y + z * z));
        x = adv[3 * i]; y = adv[3 * i + 1]; z = adv[3 * i + 2];
        advP[i] = make_float4(x, y, z, 0.5f * (x * x + y * y + z * z));
    }
}

__device__ __forceinline__ float embed6(float t, unsigned eb) {
    return __uint_as_float((__float_as_uint(t) & 0xFFFFFFC0u) | eb);  // v_and_or_b32
}

__device__ __forceinline__ float fmed3(float a, float b, float c) {
    return __builtin_amdgcn_fmed3f(a, b, c);
}

// v: merged key; p0/p1: this lane's partials. Wave-uniform result.
// Lowest matching lane = smallest global index (j = 64k + lane).
__device__ __forceinline__ int recover_j(float v, float p0, float p1) {
    unsigned long long m = __ballot((p0 == v) || (p1 == v));
    const int lane = (int)__ffsll(m) - 1;
    const int k = (NK - 1) - (int)(__float_as_uint(v) & (unsigned)(NK - 1));
    return (k << 6) | lane;
}

__device__ __forceinline__ float unit_absdot4(const float4* __restrict__ pc, int i,
                                              float px, float py, float pz,
                                              float nx, float ny, float nz) {
    const float4 c = pc[i];
    const float vx = c.x - px, vy = c.y - py, vz = c.z - pz;
    const float s  = vx * vx + vy * vy + vz * vz + 1e-12f;
    return fabsf((vx * nx + vy * ny + vz * nz) * (1.0f / sqrtf(s)));
}

__global__ __launch_bounds__(256, 4) void knn_kernel(
    const float4* __restrict__ oriP, const float4* __restrict__ advP,
    const float* __restrict__ nrm, float* __restrict__ partial,
    float* __restrict__ out, int use_partial)
{
    const int tid = threadIdx.x;
    const int ch  = tid & 63;          // chunk = lane
    const int qs  = tid >> 6;          // wave id 0..3
    const int b   = blockIdx.x >> 8;   // / (N/QPB = 256)
    const int qt  = blockIdx.x & 255;
    const int qb  = qt * QPB + qs * QPW;   // first query of this wave

    const float4* __restrict__ ob = oriP + (size_t)b * NN;
    const float4* __restrict__ ab = advP + (size_t)b * NN;
    const float*  __restrict__ nb = nrm  + (size_t)b * NN * 3;

    float4 qo[QPW], qa[QPW];
    #pragma unroll
    for (int i = 0; i < QPW; ++i) { qo[i] = ob[qb + i]; qa[i] = ab[qb + i]; }

    // top-2 trackers (max = closest); self is zapped at its (uniform) step.
    float oA[QPW], oB[QPW], aA[QPW], aB[QPW], mm[QPW];
    #pragma unroll
    for (int i = 0; i < QPW; ++i) {
        oA[i] = NEGBIG; oB[i] = NEGBIG;
        aA[i] = NEGBIG; aB[i] = NEGBIG;
        mm[i] = NEGBIG;
    }

    const int kself = qb >> 6;         // all 4 queries share one self step
    const int sl    = qb & 63;         // self lanes sl..sl+3

    const float4* __restrict__ op = ob + ch;
    const float4* __restrict__ ap = ab + ch;

    // one step: 12 dots (3 matrices x 4 queries) + top-2/argmax updates
    auto stepf = [&](const float4& co, const float4& ca, unsigned eb, bool selfstep) {
        float ko[QPW], ka[QPW], km[QPW];
        #pragma unroll
        for (int i = 0; i < QPW; ++i) {
            float t;
            t = fmaf(qo[i].z, co.z, -co.w); t = fmaf(qo[i].y, co.y, t); t = fmaf(qo[i].x, co.x, t);
            ko[i] = embed6(t, eb);
            t = fmaf(qa[i].z, co.z, -co.w); t = fmaf(qa[i].y, co.y, t); t = fmaf(qa[i].x, co.x, t);
            km[i] = embed6(t, eb);
            t = fmaf(qa[i].z, ca.z, -ca.w); t = fmaf(qa[i].y, ca.y, t); t = fmaf(qa[i].x, ca.x, t);
            ka[i] = embed6(t, eb);
        }
        if (selfstep) {                 // wave-uniform branch, taken once in 64
            #pragma unroll
            for (int i = 0; i < QPW; ++i) {
                const bool s = (ch == sl + i);
                ko[i] = s ? NEGBIG : ko[i];   // self excluded from ori-ori
                ka[i] = s ? NEGBIG : ka[i];   // self excluded from adv-adv
                // km (adv->ori argmax) keeps self: ref argmin is over ALL ori
            }
        }
        #pragma unroll
        for (int i = 0; i < QPW; ++i) {
            oB[i] = fmed3(oA[i], oB[i], ko[i]); oA[i] = fmaxf(oA[i], ko[i]);
            aB[i] = fmed3(aA[i], aB[i], ka[i]); aA[i] = fmaxf(aA[i], ka[i]);
            mm[i] = fmaxf(mm[i], km[i]);
        }
    };

    // software pipeline, prefetch distance 2; rotations become renames
    // under unroll 2; last 2 steps peeled (no OOB prefetch).
    float4 c0o = op[0 * CPB], c0a = ap[0 * CPB];
    float4 c1o = op[1 * CPB], c1a = ap[1 * CPB];

    #pragma unroll 2
    for (int k = 0; k < NK - 2; ++k) {
        const float4 c2o = op[(k + 2) * CPB];
        const float4 c2a = ap[(k + 2) * CPB];
        stepf(c0o, c0a, (unsigned)(NK - 1 - k), k == kself);
        c0o = c1o; c0a = c1a;
        c1o = c2o; c1a = c2a;
    }
    stepf(c0o, c0a, 1u, (NK - 2) == kself);
    stepf(c1o, c1a, 0u, (NK - 1) == kself);

    // save per-lane partials for index recovery
    float soA[QPW], soB[QPW], saA[QPW], saB[QPW], sm[QPW];
    #pragma unroll
    for (int i = 0; i < QPW; ++i) {
        soA[i] = oA[i]; soB[i] = oB[i];
        saA[i] = aA[i]; saB[i] = aB[i];
        sm[i]  = mm[i];
    }

    // wave butterfly top-2 merge: A=max(a0,b0); B=max(min(a0,b0),max(a1,b1))
    #pragma unroll
    for (int off = 1; off < 64; off <<= 1) {
        #pragma unroll
        for (int i = 0; i < QPW; ++i) {
            float r0, r1, mn;
            r0 = __shfl_xor(oA[i], off); r1 = __shfl_xor(oB[i], off);
            mn = fminf(oA[i], r0); oA[i] = fmaxf(oA[i], r0); oB[i] = fmaxf(mn, fmaxf(oB[i], r1));
            r0 = __shfl_xor(aA[i], off); r1 = __shfl_xor(aB[i], off);
            mn = fminf(aA[i], r0); aA[i] = fmaxf(aA[i], r0); aB[i] = fmaxf(mn, fmaxf(aB[i], r1));
            mm[i] = fmaxf(mm[i], __shfl_xor(mm[i], off));
        }
    }

    // recover global candidate indices (wave-uniform, ballot-based)
    int jo0[QPW], jo1[QPW], ja0[QPW], ja1[QPW], jm[QPW];
    #pragma unroll
    for (int i = 0; i < QPW; ++i) {
        jo0[i] = recover_j(oA[i], soA[i], soB[i]);
        jo1[i] = recover_j(oB[i], soA[i], soB[i]);
        ja0[i] = recover_j(aA[i], saA[i], saB[i]);
        ja1[i] = recover_j(aB[i], saA[i], saB[i]);
        jm[i]  = recover_j(mm[i], sm[i], sm[i]);
    }

    float val = 0.0f;
    if (ch < QPW) {                     // lane i -> query qb+i
        // pointer-free, constant-index selection (keeps arrays SROA-able)
        int io0 = 0, io1 = 0, ia0 = 0, ia1 = 0, im = 0;
        float4 qoS = qo[0], qaS = qa[0];
        #pragma unroll
        for (int i = 1; i < QPW; ++i) {
            if (ch == i) {
                io0 = jo0[i]; io1 = jo1[i];
                ia0 = ja0[i]; ia1 = ja1[i];
                im  = jm[i];
                qoS = qo[i];  qaS = qa[i];
            }
        }
        if (ch == 0) {
            io0 = jo0[0]; io1 = jo1[0];
            ia0 = ja0[0]; ia1 = ja1[0];
            im  = jm[0];
        }
        const int q = qb + ch;

        const float nx = nb[3 * q], ny = nb[3 * q + 1], nz = nb[3 * q + 2];
        const float ok = 0.5f * (unit_absdot4(ob, io0, qoS.x, qoS.y, qoS.z, nx, ny, nz) +
                                 unit_absdot4(ob, io1, qoS.x, qoS.y, qoS.z, nx, ny, nz));
        const float ax = nb[3 * im], ay = nb[3 * im + 1], az = nb[3 * im + 2];
        const float ak = 0.5f * (unit_absdot4(ab, ia0, qaS.x, qaS.y, qaS.z, ax, ay, az) +
                                 unit_absdot4(ab, ia1, qaS.x, qaS.y, qaS.z, ax, ay, az));
        const float d = ak - ok;
        val = d * d;
    }
    val += __shfl_down(val, 2);         // lanes 0..3 -> lane 0
    val += __shfl_down(val, 1);

    __shared__ float sval[4];
    if (ch == 0) sval[qs] = val;
    __syncthreads();
    if (tid == 0) {
        const float s = sval[0] + sval[1] + sval[2] + sval[3];
        if (use_partial) partial[blockIdx.x] = s;
        else             atomicAdd(out, s * (1.0f / (float)(BB * NN)));
    }
}

__global__ __launch_bounds__(256) void reduce_kernel(
    const float* __restrict__ partial, float* __restrict__ out)
{
    const int tid = threadIdx.x;
    float s = 0.0f;
    #pragma unroll
    for (int i = tid; i < NBLK; i += 256) s += partial[i];
    #pragma unroll
    for (int off = 32; off > 0; off >>= 1) s += __shfl_down(s, off);
    __shared__ float ls[4];
    if ((tid & 63) == 0) ls[tid >> 6] = s;
    __syncthreads();
    if (tid == 0)
        out[0] = (ls[0] + ls[1] + ls[2] + ls[3]) * (1.0f / (float)(BB * NN));
}

extern "C" void kernel_launch(void* const* d_in, const int* in_sizes, int n_in,
                              void* d_out, int out_size, void* d_ws, size_t ws_size,
                              hipStream_t stream) {
    const float* ori = (const float*)d_in[0];
    const float* adv = (const float*)d_in[1];
    const float* nrm = (const float*)d_in[2];
    float* out = (float*)d_out;

    float4* oriP = (float4*)d_ws;                    // 256 KB
    float4* advP = oriP + (size_t)BB * NN;           // 256 KB
    float*  part = (float*)(advP + (size_t)BB * NN); // 4 KB
    const size_t need = (size_t)2 * BB * NN * sizeof(float4) + NBLK * sizeof(float);
    const int use_partial = (ws_size >= need) ? 1 : 0;

    if (!use_partial)
        hipMemsetAsync(out, 0, sizeof(float), stream);

    hipLaunchKernelGGL(pack_kernel, dim3((BB * NN + 255) / 256), dim3(256), 0, stream,
                       ori, adv, oriP, advP);
    hipLaunchKernelGGL(knn_kernel, dim3(NBLK), dim3(256), 0, stream,
                       oriP, advP, nrm, part, out, use_partial);
    if (use_partial)
        hipLaunchKernelGGL(reduce_kernel, dim3(1), dim3(256), 0, stream, part, out);
}